// Round 4
// baseline (787.908 us; speedup 1.0000x reference)
//
#include <hip/hip_runtime.h>

// ---------------------------------------------------------------------------
// DNANet round 3: dst-major attention with dim-major KV layout and a
// software-pipelined (unroll-2, depth-4) gather loop.
// N=50000 nodes, E=600000 edges (+N self loops), HID=64, HEADS=4, d=16.
//
// KV layout: [node][dim(64)][6] = {k0,k1,k2,v0,v1,v2}, 1536 B per node.
// Per edge a lane loads 3 x float2 (8B-aligned). dinv[src] folded into V.
//
// Workspace (~115 MB): dinv N f | cnt N i | offs N+1 i | cursor N i |
//   aux 64 i | src_sorted (E+N) i | q N*64 f | KV N*384 f | sA,sB N*64 f
// ---------------------------------------------------------------------------

__global__ __launch_bounds__(256) void hist_dst_k(const int* __restrict__ dst,
                                                  int* __restrict__ cnt, int E) {
    int e = blockIdx.x * 256 + threadIdx.x;
    if (e < E) atomicAdd(&cnt[dst[e]], 1);
}

// dinv = rsqrt(cnt + 1)   (+1 = self loop)
__global__ __launch_bounds__(256) void dinv_from_cnt_k(const int* __restrict__ cnt,
                                                       float* __restrict__ dinv, int n) {
    int i = blockIdx.x * 256 + threadIdx.x;
    if (i < n) dinv[i] = rsqrtf((float)(cnt[i] + 1));
}

// Hierarchical exclusive scan of (cnt[i]+1), stage 1: 1024-elem chunks.
__global__ __launch_bounds__(256) void scan1_k(const int* __restrict__ cnt,
                                               int* __restrict__ excl,
                                               int* __restrict__ aux, int N) {
    __shared__ int wtot[4];
    int b = blockIdx.x, t = threadIdx.x;
    int lane = t & 63, w = t >> 6;
    int base = b * 1024 + t * 4;
    int v0 = (base + 0 < N) ? cnt[base + 0] + 1 : 0;
    int v1 = (base + 1 < N) ? cnt[base + 1] + 1 : 0;
    int v2 = (base + 2 < N) ? cnt[base + 2] + 1 : 0;
    int v3 = (base + 3 < N) ? cnt[base + 3] + 1 : 0;
    int s = v0 + v1 + v2 + v3;
    int incl = s;
#pragma unroll
    for (int off = 1; off < 64; off <<= 1) {
        int u = __shfl_up(incl, off);
        if (lane >= off) incl += u;
    }
    if (lane == 63) wtot[w] = incl;
    __syncthreads();
    int wb = 0;
#pragma unroll
    for (int j = 0; j < 4; ++j) if (j < w) wb += wtot[j];
    int ex = wb + incl - s;
    if (base + 0 < N) excl[base + 0] = ex;
    if (base + 1 < N) excl[base + 1] = ex + v0;
    if (base + 2 < N) excl[base + 2] = ex + v0 + v1;
    if (base + 3 < N) excl[base + 3] = ex + v0 + v1 + v2;
    if (t == 0) aux[b] = wtot[0] + wtot[1] + wtot[2] + wtot[3];
}

// Stage 2: single-wave scan of chunk totals (nb <= 64; N <= 65536).
__global__ __launch_bounds__(64) void scan_aux_k(int* __restrict__ aux, int nb,
                                                 int* __restrict__ total) {
    int lane = threadIdx.x;
    int v = (lane < nb) ? aux[lane] : 0;
    int incl = v;
#pragma unroll
    for (int off = 1; off < 64; off <<= 1) {
        int u = __shfl_up(incl, off);
        if (lane >= off) incl += u;
    }
    if (lane < nb) aux[lane] = incl - v;
    if (lane == 63) total[0] = incl;
}

// Stage 3: add chunk bases; mirror into cursor.
__global__ __launch_bounds__(256) void scan_add_k(int* __restrict__ offs,
                                                  const int* __restrict__ aux,
                                                  int* __restrict__ cursor, int N) {
    int i = blockIdx.x * 256 + threadIdx.x;
    if (i < N) {
        int o = offs[i] + aux[i >> 10];
        offs[i] = o;
        cursor[i] = o;
    }
}

__global__ __launch_bounds__(256) void scatter_dst_k(const int* __restrict__ src,
                                                     const int* __restrict__ dst,
                                                     int* __restrict__ cursor,
                                                     int* __restrict__ src_sorted,
                                                     int E, int N) {
    int e = blockIdx.x * 256 + threadIdx.x;
    int M = E + N;
    if (e >= M) return;
    int s, d;
    if (e < E) { s = src[e]; d = dst[e]; }
    else       { s = d = e - E; }
    int pos = atomicAdd(&cursor[d], 1);
    src_sorted[pos] = s;
}

// y[N x 64] = x[N x 128] @ W[128 x 64] + b
__global__ __launch_bounds__(256) void lin128_64_k(const float* __restrict__ x,
                                                   const float* __restrict__ W,
                                                   const float* __restrict__ b,
                                                   float* __restrict__ y, int N) {
    __shared__ float sW[128 * 64];
    __shared__ float sb[64];
    for (int i = threadIdx.x; i < 128 * 64; i += 256) sW[i] = W[i];
    if (threadIdx.x < 64) sb[threadIdx.x] = b[threadIdx.x];
    __syncthreads();
    int row = blockIdx.x * 4 + (threadIdx.x >> 6);
    int c   = threadIdx.x & 63;
    if (row >= N) return;
    const float* xr = x + (size_t)row * 128;
    float acc = sb[c];
#pragma unroll 16
    for (int k = 0; k < 128; ++k) acc = fmaf(xr[k], sW[k * 64 + c], acc);
    y[(size_t)row * 64 + c] = acc;
}

// q = xs@Wq+bq ; KV[row][c][l] = k ; KV[row][c][3+l] = v * dinv[row]
__global__ __launch_bounds__(256) void qkv64_k(const float* __restrict__ xs,
                                               const float* __restrict__ Wq, const float* __restrict__ bq,
                                               const float* __restrict__ Wk, const float* __restrict__ bk,
                                               const float* __restrict__ Wv, const float* __restrict__ bv,
                                               const float* __restrict__ dinv,
                                               float* __restrict__ q,
                                               float* __restrict__ KV,
                                               int N, int l) {
    __shared__ float sWq[64 * 64];
    __shared__ float sWk[64 * 64];
    __shared__ float sWv[64 * 64];
    __shared__ float sbq[64], sbk[64], sbv[64];
    for (int i = threadIdx.x; i < 64 * 64; i += 256) {
        sWq[i] = Wq[i]; sWk[i] = Wk[i]; sWv[i] = Wv[i];
    }
    if (threadIdx.x < 64) {
        sbq[threadIdx.x] = bq[threadIdx.x];
        sbk[threadIdx.x] = bk[threadIdx.x];
        sbv[threadIdx.x] = bv[threadIdx.x];
    }
    __syncthreads();
    int row = blockIdx.x * 4 + (threadIdx.x >> 6);
    int c   = threadIdx.x & 63;
    if (row >= N) return;
    const float* xr = xs + (size_t)row * 64;
    float aq = sbq[c], ak = sbk[c], av = sbv[c];
#pragma unroll 16
    for (int k = 0; k < 64; ++k) {
        float xv = xr[k];
        aq = fmaf(xv, sWq[k * 64 + c], aq);
        ak = fmaf(xv, sWk[k * 64 + c], ak);
        av = fmaf(xv, sWv[k * 64 + c], av);
    }
    q[(size_t)row * 64 + c] = aq;
    float* kvp = KV + (size_t)row * 384 + c * 6;
    kvp[l]     = ak;
    kvp[3 + l] = av * dinv[row];
}

// One dst node per 64-lane wave; unroll-2 / depth-4 pipelined gather.
// Per edge, per lane: 3 x float2 at KV2[s*192 + lane*3 + {0,1,2}]
//   = (k0,k1) (k2,v0) (v1,v2).
template <int L>
__global__ __launch_bounds__(256) void attn_dst_k(const int* __restrict__ offs,
                                                  const int* __restrict__ src_sorted,
                                                  const float* __restrict__ dinv,
                                                  const float* __restrict__ q,
                                                  const float* __restrict__ KV,
                                                  float* __restrict__ out,
                                                  int N) {
    int d    = (blockIdx.x * 256 + threadIdx.x) >> 6;
    int lane = threadIdx.x & 63;
    if (d >= N) return;
    int beg = offs[d], end = offs[d + 1];
    float qv  = (L > 1) ? q[(size_t)d * 64 + lane] : 0.0f;
    float acc = 0.0f;
    const float2* KV2 = (const float2*)KV;

    for (int base = beg; base < end; base += 64) {
        int m = end - base;
        if (m > 64) m = 64;
        int sid = (base + lane < end) ? src_sorted[base + lane] : 0;
        int mm1 = m - 1;

#define SRC_AT(i) __shfl(sid, ((i) < mm1 ? (i) : mm1))
#define LOADE(s, r0, r1, r2) { const float2* _p = KV2 + (size_t)(s) * 192 + lane * 3; \
                               if (L > 1) r0 = _p[0]; r1 = _p[1]; if (L > 2) r2 = _p[2]; \
                               else if (L == 2) r2 = _p[2]; }
        // (L==2 still loads r2 for v1 = r2.x; L==1 uses only r1.y)

        int sA = SRC_AT(0), sB = SRC_AT(1);
        float2 A0, A1, A2, B0, B1, B2;
        A0 = B0 = A2 = B2 = make_float2(0.f, 0.f);
        LOADE(sA, A0, A1, A2);
        LOADE(sB, B0, B1, B2);

        for (int i = 0; i < m; i += 2) {
            int sC = SRC_AT(i + 2), sD = SRC_AT(i + 3);
            float2 C0, C1, C2, D0, D1, D2;
            C0 = D0 = C2 = D2 = make_float2(0.f, 0.f);
            LOADE(sC, C0, C1, C2);
            LOADE(sD, D0, D1, D2);

            // ---- edge i (always valid) ----
            {
                if (L == 1) {
                    acc += A1.y;
                } else {
                    float p0 = qv * A0.x;
                    float p1 = qv * A0.y;
                    float p2 = (L > 2) ? qv * A1.x : 0.f;
#pragma unroll
                    for (int mk = 8; mk >= 1; mk >>= 1) {
                        p0 += __shfl_xor(p0, mk);
                        p1 += __shfl_xor(p1, mk);
                        if (L > 2) p2 += __shfl_xor(p2, mk);
                    }
                    float s0 = p0 * 0.25f, s1 = p1 * 0.25f, s2 = p2 * 0.25f;
                    float mx = fmaxf(s0, s1);
                    if (L > 2) mx = fmaxf(mx, s2);
                    float w0 = __expf(s0 - mx);
                    float w1 = __expf(s1 - mx);
                    float w2 = (L > 2) ? __expf(s2 - mx) : 0.f;
                    float inv = __builtin_amdgcn_rcpf(w0 + w1 + w2);
                    float msg = w0 * A1.y;
                    msg = fmaf(w1, A2.x, msg);
                    if (L > 2) msg = fmaf(w2, A2.y, msg);
                    acc = fmaf(msg, inv, acc);
                }
            }
            // ---- edge i+1 (guarded) ----
            if (i + 1 < m) {
                if (L == 1) {
                    acc += B1.y;
                } else {
                    float p0 = qv * B0.x;
                    float p1 = qv * B0.y;
                    float p2 = (L > 2) ? qv * B1.x : 0.f;
#pragma unroll
                    for (int mk = 8; mk >= 1; mk >>= 1) {
                        p0 += __shfl_xor(p0, mk);
                        p1 += __shfl_xor(p1, mk);
                        if (L > 2) p2 += __shfl_xor(p2, mk);
                    }
                    float s0 = p0 * 0.25f, s1 = p1 * 0.25f, s2 = p2 * 0.25f;
                    float mx = fmaxf(s0, s1);
                    if (L > 2) mx = fmaxf(mx, s2);
                    float w0 = __expf(s0 - mx);
                    float w1 = __expf(s1 - mx);
                    float w2 = (L > 2) ? __expf(s2 - mx) : 0.f;
                    float inv = __builtin_amdgcn_rcpf(w0 + w1 + w2);
                    float msg = w0 * B1.y;
                    msg = fmaf(w1, B2.x, msg);
                    if (L > 2) msg = fmaf(w2, B2.y, msg);
                    acc = fmaf(msg, inv, acc);
                }
            }
            A0 = C0; A1 = C1; A2 = C2;
            B0 = D0; B1 = D1; B2 = D2;
        }
#undef SRC_AT
#undef LOADE
    }
    out[(size_t)d * 64 + lane] = acc * dinv[d];
}

// y[N x 16] = xs[N x 64] @ W[64 x 16] + b
__global__ __launch_bounds__(256) void out_proj_k(const float* __restrict__ xs,
                                                  const float* __restrict__ W,
                                                  const float* __restrict__ b,
                                                  float* __restrict__ y, int N) {
    __shared__ float sW[64 * 16];
    __shared__ float sb[16];
    for (int i = threadIdx.x; i < 64 * 16; i += 256) sW[i] = W[i];
    if (threadIdx.x < 16) sb[threadIdx.x] = b[threadIdx.x];
    __syncthreads();
    int row = blockIdx.x * 16 + (threadIdx.x >> 4);
    int c   = threadIdx.x & 15;
    if (row >= N) return;
    const float* xr = xs + (size_t)row * 64;
    float acc = sb[c];
#pragma unroll 16
    for (int k = 0; k < 64; ++k) acc = fmaf(xr[k], sW[k * 16 + c], acc);
    y[(size_t)row * 16 + c] = acc;
}

extern "C" void kernel_launch(void* const* d_in, const int* in_sizes, int n_in,
                              void* d_out, int out_size, void* d_ws, size_t ws_size,
                              hipStream_t stream) {
    const float* x     = (const float*)d_in[0];
    const int*   ei    = (const int*)d_in[1];
    const float* W_lin = (const float*)d_in[2];
    const float* b_lin = (const float*)d_in[3];
    const float* Wq    = (const float*)d_in[4];
    const float* bq    = (const float*)d_in[5];
    const float* Wk    = (const float*)d_in[6];
    const float* bk    = (const float*)d_in[7];
    const float* Wv    = (const float*)d_in[8];
    const float* bv    = (const float*)d_in[9];
    const float* W_out = (const float*)d_in[10];
    const float* b_out = (const float*)d_in[11];
    float* out = (float*)d_out;

    const int N = in_sizes[0] / 128;
    const int E = in_sizes[1] / 2;
    const int M = E + N;
    const int* srcp = ei;
    const int* dstp = ei + E;

    char* wsb = (char*)d_ws;
    float* dinv       = (float*)wsb;  wsb += (size_t)N * sizeof(float);
    int*   cnt        = (int*)wsb;    wsb += (size_t)N * sizeof(int);
    int*   offs       = (int*)wsb;    wsb += (size_t)(N + 1) * sizeof(int);
    int*   cursor     = (int*)wsb;    wsb += (size_t)N * sizeof(int);
    int*   aux        = (int*)wsb;    wsb += 64 * sizeof(int);
    int*   src_sorted = (int*)wsb;    wsb += (size_t)M * sizeof(int);
    float* qb         = (float*)wsb;  wsb += (size_t)N * 64 * sizeof(float);
    float* KVb        = (float*)wsb;  wsb += (size_t)N * 384 * sizeof(float);
    float* sA         = (float*)wsb;  wsb += (size_t)N * 64 * sizeof(float);
    float* sB         = (float*)wsb;

    const int gN   = (N + 255) / 256;
    const int gE   = (E + 255) / 256;
    const int gM   = (M + 255) / 256;
    const int gRow = (N + 3) / 4;          // 4 waves (rows/nodes) per block
    const int nb   = (N + 1023) / 1024;    // scan chunks (<= 64 for N <= 65536)

    // in-degree (self loop folded as +1 downstream) -> dinv, dst-CSR
    hipMemsetAsync(cnt, 0, (size_t)N * sizeof(int), stream);
    hist_dst_k<<<gE, 256, 0, stream>>>(dstp, cnt, E);
    dinv_from_cnt_k<<<gN, 256, 0, stream>>>(cnt, dinv, N);
    scan1_k<<<nb, 256, 0, stream>>>(cnt, offs, aux, N);
    scan_aux_k<<<1, 64, 0, stream>>>(aux, nb, offs + N);
    scan_add_k<<<gN, 256, 0, stream>>>(offs, aux, cursor, N);
    scatter_dst_k<<<gM, 256, 0, stream>>>(srcp, dstp, cursor, src_sorted, E, N);

    // slice 0
    lin128_64_k<<<gRow, 256, 0, stream>>>(x, W_lin, b_lin, sA, N);

    float* cur = sA;
    float* nxt = sB;
    for (int t = 0; t < 3; ++t) {
        qkv64_k<<<gRow, 256, 0, stream>>>(cur, Wq, bq, Wk, bk, Wv, bv, dinv,
                                          qb, KVb, N, t);
        switch (t) {
            case 0: attn_dst_k<1><<<gRow, 256, 0, stream>>>(offs, src_sorted, dinv, qb, KVb, nxt, N); break;
            case 1: attn_dst_k<2><<<gRow, 256, 0, stream>>>(offs, src_sorted, dinv, qb, KVb, nxt, N); break;
            case 2: attn_dst_k<3><<<gRow, 256, 0, stream>>>(offs, src_sorted, dinv, qb, KVb, nxt, N); break;
        }
        float* tmp = cur; cur = nxt; nxt = tmp;
    }

    out_proj_k<<<gRow, 256, 0, stream>>>(cur, W_out, b_out, out, N);
}

// Round 5
// 484.535 us; speedup vs baseline: 1.6261x; 1.6261x over previous
//
#include <hip/hip_runtime.h>

// ---------------------------------------------------------------------------
// DNANet round 4: dst-major attention over bf16-packed per-slice K/V planes.
// N=50000 nodes, E=600000 edges (+N self loops), HID=64, HEADS=4, d=16.
//
// plane_l[node][dim] : u32 = bf16(k_l) | bf16(v_l * dinv[node]) << 16  (256 B/node)
// v0 plane           : u16 = bf16(v_0 * dinv[node])                    (128 B/node)
// Per edge gather: L dword loads per lane (L=1: one ushort load).
// q fp32, all accumulation fp32. Attn is fabric-BW-bound -> bytes/edge halved.
//
// Workspace (~86 MB): dinv N f | cnt N i | offs N+1 i | cursor N i | aux 64 i |
//   src_sorted (E+N) i | q N*64 f | planes 3*N*64 u32 | V0 N*64 u16 | sA,sB N*64 f
// ---------------------------------------------------------------------------

__device__ inline unsigned short bf16_rne(float f) {
    unsigned int u = __float_as_uint(f);
    unsigned int r = u + 0x7FFFu + ((u >> 16) & 1u);
    return (unsigned short)(r >> 16);
}

__global__ __launch_bounds__(256) void hist_dst_k(const int* __restrict__ dst,
                                                  int* __restrict__ cnt, int E) {
    int e = blockIdx.x * 256 + threadIdx.x;
    if (e < E) atomicAdd(&cnt[dst[e]], 1);
}

// dinv = rsqrt(cnt + 1)   (+1 = self loop)
__global__ __launch_bounds__(256) void dinv_from_cnt_k(const int* __restrict__ cnt,
                                                       float* __restrict__ dinv, int n) {
    int i = blockIdx.x * 256 + threadIdx.x;
    if (i < n) dinv[i] = rsqrtf((float)(cnt[i] + 1));
}

// Hierarchical exclusive scan of (cnt[i]+1), stage 1: 1024-elem chunks.
__global__ __launch_bounds__(256) void scan1_k(const int* __restrict__ cnt,
                                               int* __restrict__ excl,
                                               int* __restrict__ aux, int N) {
    __shared__ int wtot[4];
    int b = blockIdx.x, t = threadIdx.x;
    int lane = t & 63, w = t >> 6;
    int base = b * 1024 + t * 4;
    int v0 = (base + 0 < N) ? cnt[base + 0] + 1 : 0;
    int v1 = (base + 1 < N) ? cnt[base + 1] + 1 : 0;
    int v2 = (base + 2 < N) ? cnt[base + 2] + 1 : 0;
    int v3 = (base + 3 < N) ? cnt[base + 3] + 1 : 0;
    int s = v0 + v1 + v2 + v3;
    int incl = s;
#pragma unroll
    for (int off = 1; off < 64; off <<= 1) {
        int u = __shfl_up(incl, off);
        if (lane >= off) incl += u;
    }
    if (lane == 63) wtot[w] = incl;
    __syncthreads();
    int wb = 0;
#pragma unroll
    for (int j = 0; j < 4; ++j) if (j < w) wb += wtot[j];
    int ex = wb + incl - s;
    if (base + 0 < N) excl[base + 0] = ex;
    if (base + 1 < N) excl[base + 1] = ex + v0;
    if (base + 2 < N) excl[base + 2] = ex + v0 + v1;
    if (base + 3 < N) excl[base + 3] = ex + v0 + v1 + v2;
    if (t == 0) aux[b] = wtot[0] + wtot[1] + wtot[2] + wtot[3];
}

// Stage 2: single-wave scan of chunk totals (nb <= 64; N <= 65536).
__global__ __launch_bounds__(64) void scan_aux_k(int* __restrict__ aux, int nb,
                                                 int* __restrict__ total) {
    int lane = threadIdx.x;
    int v = (lane < nb) ? aux[lane] : 0;
    int incl = v;
#pragma unroll
    for (int off = 1; off < 64; off <<= 1) {
        int u = __shfl_up(incl, off);
        if (lane >= off) incl += u;
    }
    if (lane < nb) aux[lane] = incl - v;
    if (lane == 63) total[0] = incl;
}

// Stage 3: add chunk bases; mirror into cursor.
__global__ __launch_bounds__(256) void scan_add_k(int* __restrict__ offs,
                                                  const int* __restrict__ aux,
                                                  int* __restrict__ cursor, int N) {
    int i = blockIdx.x * 256 + threadIdx.x;
    if (i < N) {
        int o = offs[i] + aux[i >> 10];
        offs[i] = o;
        cursor[i] = o;
    }
}

__global__ __launch_bounds__(256) void scatter_dst_k(const int* __restrict__ src,
                                                     const int* __restrict__ dst,
                                                     int* __restrict__ cursor,
                                                     int* __restrict__ src_sorted,
                                                     int E, int N) {
    int e = blockIdx.x * 256 + threadIdx.x;
    int M = E + N;
    if (e >= M) return;
    int s, d;
    if (e < E) { s = src[e]; d = dst[e]; }
    else       { s = d = e - E; }
    int pos = atomicAdd(&cursor[d], 1);
    src_sorted[pos] = s;
}

// y[N x 64] = x[N x 128] @ W[128 x 64] + b ; 16 rows/block (4 rows/thread).
__global__ __launch_bounds__(256) void lin128_64_k(const float* __restrict__ x,
                                                   const float* __restrict__ W,
                                                   const float* __restrict__ b,
                                                   float* __restrict__ y, int N) {
    __shared__ float sW[128 * 64];
    __shared__ float sb[64];
    for (int i = threadIdx.x; i < 128 * 64; i += 256) sW[i] = W[i];
    if (threadIdx.x < 64) sb[threadIdx.x] = b[threadIdx.x];
    __syncthreads();
    int w = threadIdx.x >> 6, c = threadIdx.x & 63;
    int r0 = blockIdx.x * 16 + w * 4;
    if (r0 >= N) return;
    const float* xr[4];
#pragma unroll
    for (int j = 0; j < 4; ++j) {
        int r = r0 + j; if (r > N - 1) r = N - 1;
        xr[j] = x + (size_t)r * 128;
    }
    float acc[4];
#pragma unroll
    for (int j = 0; j < 4; ++j) acc[j] = sb[c];
    for (int k = 0; k < 128; ++k) {
        float wv = sW[k * 64 + c];
#pragma unroll
        for (int j = 0; j < 4; ++j) acc[j] = fmaf(xr[j][k], wv, acc[j]);
    }
#pragma unroll
    for (int j = 0; j < 4; ++j) {
        int r = r0 + j;
        if (r < N) y[(size_t)r * 64 + c] = acc[j];
    }
}

// q = xs@Wq+bq (fp32) ; plane[r][c] = pack(bf16(k), bf16(v*dinv)) ;
// if l==0 also v0p[r][c] = bf16(v*dinv). 16 rows/block, 4 rows/thread.
__global__ __launch_bounds__(256) void qkv_pack_k(const float* __restrict__ xs,
                                                  const float* __restrict__ Wq, const float* __restrict__ bq,
                                                  const float* __restrict__ Wk, const float* __restrict__ bk,
                                                  const float* __restrict__ Wv, const float* __restrict__ bv,
                                                  const float* __restrict__ dinv,
                                                  float* __restrict__ q,
                                                  unsigned int* __restrict__ plane,
                                                  unsigned short* __restrict__ v0p,
                                                  int N) {
    __shared__ float sWq[64 * 64];
    __shared__ float sWk[64 * 64];
    __shared__ float sWv[64 * 64];
    __shared__ float sbq[64], sbk[64], sbv[64];
    for (int i = threadIdx.x; i < 64 * 64; i += 256) {
        sWq[i] = Wq[i]; sWk[i] = Wk[i]; sWv[i] = Wv[i];
    }
    if (threadIdx.x < 64) {
        sbq[threadIdx.x] = bq[threadIdx.x];
        sbk[threadIdx.x] = bk[threadIdx.x];
        sbv[threadIdx.x] = bv[threadIdx.x];
    }
    __syncthreads();
    int w = threadIdx.x >> 6, c = threadIdx.x & 63;
    int r0 = blockIdx.x * 16 + w * 4;
    if (r0 >= N) return;
    const float* xr[4];
#pragma unroll
    for (int j = 0; j < 4; ++j) {
        int r = r0 + j; if (r > N - 1) r = N - 1;
        xr[j] = xs + (size_t)r * 64;
    }
    float aq[4], ak[4], av[4];
#pragma unroll
    for (int j = 0; j < 4; ++j) { aq[j] = sbq[c]; ak[j] = sbk[c]; av[j] = sbv[c]; }
    for (int k = 0; k < 64; ++k) {
        float wq = sWq[k * 64 + c], wk = sWk[k * 64 + c], wv = sWv[k * 64 + c];
#pragma unroll
        for (int j = 0; j < 4; ++j) {
            float xv = xr[j][k];
            aq[j] = fmaf(xv, wq, aq[j]);
            ak[j] = fmaf(xv, wk, ak[j]);
            av[j] = fmaf(xv, wv, av[j]);
        }
    }
#pragma unroll
    for (int j = 0; j < 4; ++j) {
        int r = r0 + j;
        if (r >= N) break;
        q[(size_t)r * 64 + c] = aq[j];
        unsigned short kb = bf16_rne(ak[j]);
        unsigned short vb = bf16_rne(av[j] * dinv[r]);
        plane[(size_t)r * 64 + c] = (unsigned int)kb | ((unsigned int)vb << 16);
        if (v0p) v0p[(size_t)r * 64 + c] = vb;
    }
}

// One dst node per 64-lane wave; L dword (or 1 ushort) gathers per edge.
template <int L>
__global__ __launch_bounds__(256) void attn_dst_k(const int* __restrict__ offs,
                                                  const int* __restrict__ src_sorted,
                                                  const float* __restrict__ dinv,
                                                  const float* __restrict__ q,
                                                  const unsigned int* __restrict__ P0,
                                                  const unsigned int* __restrict__ P1,
                                                  const unsigned int* __restrict__ P2,
                                                  const unsigned short* __restrict__ V0,
                                                  float* __restrict__ out,
                                                  int N) {
    int d    = (blockIdx.x * 256 + threadIdx.x) >> 6;
    int lane = threadIdx.x & 63;
    if (d >= N) return;
    int beg = offs[d], end = offs[d + 1];
    float qv  = (L > 1) ? q[(size_t)d * 64 + lane] : 0.0f;
    float acc = 0.0f;

    for (int base = beg; base < end; base += 64) {
        int m = end - base;
        if (m > 64) m = 64;
        int sid = (base + lane < end) ? src_sorted[base + lane] : 0;
#pragma unroll 4
        for (int i = 0; i < m; ++i) {
            int s = __shfl(sid, i);
            if (L == 1) {
                acc += __uint_as_float((unsigned int)V0[(size_t)s * 64 + lane] << 16);
            } else if (L == 2) {
                unsigned int u0 = P0[(size_t)s * 64 + lane];
                unsigned int u1 = P1[(size_t)s * 64 + lane];
                float k0 = __uint_as_float((u0 & 0xFFFFu) << 16);
                float v0 = __uint_as_float(u0 & 0xFFFF0000u);
                float k1 = __uint_as_float((u1 & 0xFFFFu) << 16);
                float v1 = __uint_as_float(u1 & 0xFFFF0000u);
                float p0 = qv * k0;
                float p1 = qv * k1;
#pragma unroll
                for (int mk = 8; mk >= 1; mk >>= 1) {
                    p0 += __shfl_xor(p0, mk);
                    p1 += __shfl_xor(p1, mk);
                }
                float e = __expf((p1 - p0) * 0.25f);      // / sqrt(16)
                float w0 = __builtin_amdgcn_rcpf(1.0f + e);
                float w1 = 1.0f - w0;
                acc = fmaf(w0, v0, acc);
                acc = fmaf(w1, v1, acc);
            } else {
                unsigned int u0 = P0[(size_t)s * 64 + lane];
                unsigned int u1 = P1[(size_t)s * 64 + lane];
                unsigned int u2 = P2[(size_t)s * 64 + lane];
                float k0 = __uint_as_float((u0 & 0xFFFFu) << 16);
                float v0 = __uint_as_float(u0 & 0xFFFF0000u);
                float k1 = __uint_as_float((u1 & 0xFFFFu) << 16);
                float v1 = __uint_as_float(u1 & 0xFFFF0000u);
                float k2 = __uint_as_float((u2 & 0xFFFFu) << 16);
                float v2 = __uint_as_float(u2 & 0xFFFF0000u);
                float p0 = qv * k0;
                float p1 = qv * k1;
                float p2 = qv * k2;
#pragma unroll
                for (int mk = 8; mk >= 1; mk >>= 1) {
                    p0 += __shfl_xor(p0, mk);
                    p1 += __shfl_xor(p1, mk);
                    p2 += __shfl_xor(p2, mk);
                }
                float s0 = p0 * 0.25f, s1 = p1 * 0.25f, s2 = p2 * 0.25f;
                float mx = fmaxf(fmaxf(s0, s1), s2);
                float w0 = __expf(s0 - mx);
                float w1 = __expf(s1 - mx);
                float w2 = __expf(s2 - mx);
                float inv = __builtin_amdgcn_rcpf(w0 + w1 + w2);
                float msg = w0 * v0;
                msg = fmaf(w1, v1, msg);
                msg = fmaf(w2, v2, msg);
                acc = fmaf(msg, inv, acc);
            }
        }
    }
    out[(size_t)d * 64 + lane] = acc * dinv[d];
}

// y[N x 16] = xs[N x 64] @ W[64 x 16] + b
__global__ __launch_bounds__(256) void out_proj_k(const float* __restrict__ xs,
                                                  const float* __restrict__ W,
                                                  const float* __restrict__ b,
                                                  float* __restrict__ y, int N) {
    __shared__ float sW[64 * 16];
    __shared__ float sb[16];
    for (int i = threadIdx.x; i < 64 * 16; i += 256) sW[i] = W[i];
    if (threadIdx.x < 16) sb[threadIdx.x] = b[threadIdx.x];
    __syncthreads();
    int row = blockIdx.x * 16 + (threadIdx.x >> 4);
    int c   = threadIdx.x & 15;
    if (row >= N) return;
    const float* xr = xs + (size_t)row * 64;
    float acc = sb[c];
#pragma unroll 16
    for (int k = 0; k < 64; ++k) acc = fmaf(xr[k], sW[k * 16 + c], acc);
    y[(size_t)row * 16 + c] = acc;
}

extern "C" void kernel_launch(void* const* d_in, const int* in_sizes, int n_in,
                              void* d_out, int out_size, void* d_ws, size_t ws_size,
                              hipStream_t stream) {
    const float* x     = (const float*)d_in[0];
    const int*   ei    = (const int*)d_in[1];
    const float* W_lin = (const float*)d_in[2];
    const float* b_lin = (const float*)d_in[3];
    const float* Wq    = (const float*)d_in[4];
    const float* bq    = (const float*)d_in[5];
    const float* Wk    = (const float*)d_in[6];
    const float* bk    = (const float*)d_in[7];
    const float* Wv    = (const float*)d_in[8];
    const float* bv    = (const float*)d_in[9];
    const float* W_out = (const float*)d_in[10];
    const float* b_out = (const float*)d_in[11];
    float* out = (float*)d_out;

    const int N = in_sizes[0] / 128;
    const int E = in_sizes[1] / 2;
    const int M = E + N;
    const int* srcp = ei;
    const int* dstp = ei + E;

    char* wsb = (char*)d_ws;
    float*          dinv       = (float*)wsb;           wsb += (size_t)N * sizeof(float);
    int*            cnt        = (int*)wsb;             wsb += (size_t)N * sizeof(int);
    int*            offs       = (int*)wsb;             wsb += (size_t)(N + 1) * sizeof(int);
    int*            cursor     = (int*)wsb;             wsb += (size_t)N * sizeof(int);
    int*            aux        = (int*)wsb;             wsb += 64 * sizeof(int);
    int*            src_sorted = (int*)wsb;             wsb += (size_t)M * sizeof(int);
    float*          qb         = (float*)wsb;           wsb += (size_t)N * 64 * sizeof(float);
    unsigned int*   planes     = (unsigned int*)wsb;    wsb += (size_t)3 * N * 64 * sizeof(unsigned int);
    unsigned short* V0p        = (unsigned short*)wsb;  wsb += (size_t)N * 64 * sizeof(unsigned short);
    float*          sA         = (float*)wsb;           wsb += (size_t)N * 64 * sizeof(float);
    float*          sB         = (float*)wsb;

    const int gN   = (N + 255) / 256;
    const int gE   = (E + 255) / 256;
    const int gM   = (M + 255) / 256;
    const int gRow = (N + 3) / 4;          // attn/out_proj: 4 waves per block
    const int g16  = (N + 15) / 16;        // lin/qkv: 16 rows per block
    const int nb   = (N + 1023) / 1024;    // scan chunks (<= 64 for N <= 65536)

    // in-degree (self loop folded as +1 downstream) -> dinv, dst-CSR
    hipMemsetAsync(cnt, 0, (size_t)N * sizeof(int), stream);
    hist_dst_k<<<gE, 256, 0, stream>>>(dstp, cnt, E);
    dinv_from_cnt_k<<<gN, 256, 0, stream>>>(cnt, dinv, N);
    scan1_k<<<nb, 256, 0, stream>>>(cnt, offs, aux, N);
    scan_aux_k<<<1, 64, 0, stream>>>(aux, nb, offs + N);
    scan_add_k<<<gN, 256, 0, stream>>>(offs, aux, cursor, N);
    scatter_dst_k<<<gM, 256, 0, stream>>>(srcp, dstp, cursor, src_sorted, E, N);

    // slice 0
    lin128_64_k<<<g16, 256, 0, stream>>>(x, W_lin, b_lin, sA, N);

    unsigned int* P0 = planes;
    unsigned int* P1 = planes + (size_t)N * 64;
    unsigned int* P2 = planes + (size_t)2 * N * 64;

    float* cur = sA;
    float* nxt = sB;
    for (int t = 0; t < 3; ++t) {
        qkv_pack_k<<<g16, 256, 0, stream>>>(cur, Wq, bq, Wk, bk, Wv, bv, dinv,
                                            qb, planes + (size_t)t * N * 64,
                                            (t == 0) ? V0p : (unsigned short*)nullptr, N);
        switch (t) {
            case 0: attn_dst_k<1><<<gRow, 256, 0, stream>>>(offs, src_sorted, dinv, qb, P0, P1, P2, V0p, nxt, N); break;
            case 1: attn_dst_k<2><<<gRow, 256, 0, stream>>>(offs, src_sorted, dinv, qb, P0, P1, P2, V0p, nxt, N); break;
            case 2: attn_dst_k<3><<<gRow, 256, 0, stream>>>(offs, src_sorted, dinv, qb, P0, P1, P2, V0p, nxt, N); break;
        }
        float* tmp = cur; cur = nxt; nxt = tmp;
    }

    out_proj_k<<<g16, 256, 0, stream>>>(cur, W_out, b_out, out, N);
}